// Round 3
// baseline (25879.398 us; speedup 1.0000x reference)
//
#include <hip/hip_runtime.h>
#include <stdint.h>

// Recursive Gaussian LSTM, batch-partitioned, ZERO global barriers.
// The recurrence is independent per batch row, so 4 WGs x 16 batches each run
// with no inter-WG sync at all; every WG streams the weight set from its
// XCD-private L2 each step. Workspace use is fully gated on ws_size:
//   mode  1: packed bf16 weights + f32 xW hoist  (needs ~129.5 MB)
//   mode  2: packed bf16 weights + bf16 xW hoist (needs ~65.5 MB)
//   mode  0: packed bf16 weights, x@Wih folded into phase A K=512 (~1.5 MB)
//   mode -1: NO workspace touched, f32 weights converted on the fly (slowest)

#define OSTRIDE 8388608ull  // B*T*HS

typedef float floatx4 __attribute__((ext_vector_type(4)));
typedef short bfx8 __attribute__((ext_vector_type(8)));

__device__ inline short f2bf(float f) {
  union { float f; uint32_t u; } v; v.f = f;
  uint32_t r = v.u + 0x7fffu + ((v.u >> 16) & 1u);  // RNE
  return (short)(r >> 16);
}
__device__ inline float bf2f(short s) {
  union { uint32_t u; float f; } v; v.u = ((uint32_t)(uint16_t)s) << 16;
  return v.f;
}
__device__ inline float sigm(float x) { return 1.f / (1.f + __expf(-x)); }
__device__ inline float tanhfast(float x) {
  float e = __expf(2.f * x);
  return 1.f - 2.f / (e + 1.f);
}
__device__ inline float softplusf(float x) {
  return (x > 15.f) ? x : log1pf(__expf(x));
}

// ---------------- pack weights -> bf16, column-major-K (B-frag friendly) -----
// WgP[col][k]: col<1024, k<512 (k<256 from Wih, k>=256 from Whh)
// HrepP/CrepP[col][k]: col<512, k<256
__global__ __launch_bounds__(256)
void pack_kernel(const float* __restrict__ Wih, const float* __restrict__ Whh,
                 const float* __restrict__ Hrep, const float* __restrict__ Crep,
                 short* __restrict__ WgP, short* __restrict__ HrepP,
                 short* __restrict__ CrepP) {
  int idx = blockIdx.x * 256 + threadIdx.x;
  if (idx < 524288) {
    int col = idx >> 9, k = idx & 511;
    float v = (k < 256) ? Wih[k * 1024 + col] : Whh[(k - 256) * 1024 + col];
    WgP[idx] = f2bf(v);
  } else if (idx < 655360) {
    int j = idx - 524288, col = j >> 8, k = j & 255;
    HrepP[j] = f2bf(Hrep[k * 512 + col]);
  } else {
    int j = idx - 655360, col = j >> 8, k = j & 255;
    CrepP[j] = f2bf(Crep[k * 512 + col]);
  }
}

// ---------------- xW = x @ Wih + bias, for all (t,b) -------------------------
// Output layout xW[m = t*64 + b][1024] so the recurrent kernel reads its 16
// batches of step t as one contiguous block.
__global__ __launch_bounds__(256)
void xw_gemm_kernel(const float* __restrict__ x, const short* __restrict__ WgP,
                    const float* __restrict__ bias,
                    float* __restrict__ xwf, short* __restrict__ xwh,
                    int bf16out) {
  const int gx = blockIdx.x;            // 512 M-tiles of 64 rows
  const int gy = blockIdx.y;            // 4 N-blocks of 256 cols
  const int wave = threadIdx.x >> 6, l = threadIdx.x & 63;
  const int n = l & 15, quad = l >> 4;

  floatx4 acc[4][4];
  #pragma unroll
  for (int mt = 0; mt < 4; ++mt)
    #pragma unroll
    for (int nt = 0; nt < 4; ++nt) acc[mt][nt] = 0.f;

  #pragma unroll
  for (int kt = 0; kt < 8; ++kt) {
    bfx8 a[4];
    #pragma unroll
    for (int mt = 0; mt < 4; ++mt) {
      int m = gx * 64 + mt * 16 + n;
      int t = m >> 6, b = m & 63;
      const floatx4* px =
          (const floatx4*)(x + ((size_t)b * 512 + t) * 256 + kt * 32 + quad * 8);
      floatx4 lo = px[0], hi = px[1];
      bfx8 av;
      av[0] = f2bf(lo[0]); av[1] = f2bf(lo[1]); av[2] = f2bf(lo[2]); av[3] = f2bf(lo[3]);
      av[4] = f2bf(hi[0]); av[5] = f2bf(hi[1]); av[6] = f2bf(hi[2]); av[7] = f2bf(hi[3]);
      a[mt] = av;
    }
    #pragma unroll
    for (int nt = 0; nt < 4; ++nt) {
      int col = gy * 256 + wave * 64 + nt * 16 + n;
      bfx8 bf = *(const bfx8*)(WgP + (size_t)col * 512 + kt * 32 + quad * 8);
      #pragma unroll
      for (int mt = 0; mt < 4; ++mt)
        acc[mt][nt] = __builtin_amdgcn_mfma_f32_16x16x32_bf16(a[mt], bf, acc[mt][nt], 0, 0, 0);
    }
  }
  #pragma unroll
  for (int nt = 0; nt < 4; ++nt) {
    int col = gy * 256 + wave * 64 + nt * 16 + n;
    float bv = bias[col];
    #pragma unroll
    for (int mt = 0; mt < 4; ++mt)
      #pragma unroll
      for (int r = 0; r < 4; ++r) {
        int m = gx * 64 + mt * 16 + quad * 4 + r;
        size_t o = (size_t)m * 1024 + col;
        float v = acc[mt][nt][r] + bv;
        if (bf16out) xwh[o] = f2bf(v); else xwf[o] = v;
      }
  }
}

// ---------------- recurrent kernel: 4 WGs x 16 batches, no inter-WG sync -----
__global__ __launch_bounds__(512)
void recur_kernel(const float* __restrict__ x,
                  const short* __restrict__ WgP,
                  const float* __restrict__ Wih, const float* __restrict__ Whh,
                  const float* __restrict__ bias,
                  const short* __restrict__ HrepP, const short* __restrict__ CrepP,
                  const float* __restrict__ Hrep, const float* __restrict__ Crep,
                  const float* __restrict__ eps_h, const float* __restrict__ eps_c,
                  const float* __restrict__ xwf, const short* __restrict__ xwh,
                  int xw_mode,                    // 1=f32 xW, 2=bf16 xW, 0=packed K512, -1=no-ws
                  float* __restrict__ out) {
  const int tid = threadIdx.x;
  const int wave = tid >> 6, l = tid & 63;
  const int n = l & 15, quad = l >> 4;     // MFMA roles
  const int b0 = blockIdx.x * 16;          // this WG's batch range
  const int bc = tid >> 5;                 // cell role: batch 0..15
  const int u0 = tid & 31;                 // cell role: u = u0 + 32*r

  // LDS: gate/output exchange (f32, stride 1028 kills power-of-2 conflicts);
  // h(t-1) and pre_h/pre_c as bf16 MFMA-A sources, XOR-swizzled 16B granules
  // so b128 reads spread uniformly over all 8 granule slots per 128B window.
  __shared__ float xg[16][1028];     // 65.8 KB
  __shared__ short hA[16 * 256];     // 8 KB
  __shared__ short pA[2][16 * 256];  // 16 KB

  for (int i = tid; i < 16 * 256; i += 512) hA[i] = 0;
  float c_reg[8] = {0.f, 0.f, 0.f, 0.f, 0.f, 0.f, 0.f, 0.f};
  __syncthreads();

  #pragma unroll 1
  for (int t = 0; t < 512; ++t) {
    // ---- prefetch xW (or bias) for the activation stage (cell role) ----
    float xw[4][8];
    if (xw_mode == 1) {
      const float* p = xwf + ((size_t)t * 64 + b0 + bc) * 1024;
      #pragma unroll
      for (int g = 0; g < 4; ++g)
        #pragma unroll
        for (int r = 0; r < 8; ++r) xw[g][r] = p[g * 256 + u0 + 32 * r];
    } else if (xw_mode == 2) {
      const short* p = xwh + ((size_t)t * 64 + b0 + bc) * 1024;
      #pragma unroll
      for (int g = 0; g < 4; ++g)
        #pragma unroll
        for (int r = 0; r < 8; ++r) xw[g][r] = bf2f(p[g * 256 + u0 + 32 * r]);
    } else {  // modes 0 / -1: bias only, x folded into phase A
      #pragma unroll
      for (int g = 0; g < 4; ++g)
        #pragma unroll
        for (int r = 0; r < 8; ++r) xw[g][r] = bias[g * 256 + u0 + 32 * r];
    }

    // ---- phase A ----
    floatx4 acc[8];
    #pragma unroll
    for (int nt = 0; nt < 8; ++nt) acc[nt] = 0.f;
    if (xw_mode > 0) {
      // h(t-1) @ Whh only, K=256, packed bf16 weights streamed from L2
      #pragma unroll
      for (int kt = 0; kt < 8; ++kt) {
        bfx8 a = *(const bfx8*)&hA[(n * 256 + kt * 32 + quad * 8) ^ ((n & 7) << 3)];
        #pragma unroll
        for (int nt = 0; nt < 8; ++nt) {
          int col = wave * 128 + nt * 16 + n;
          bfx8 bf = *(const bfx8*)(WgP + (size_t)col * 512 + 256 + kt * 32 + quad * 8);
          acc[nt] = __builtin_amdgcn_mfma_f32_16x16x32_bf16(a, bf, acc[nt], 0, 0, 0);
        }
      }
    } else if (xw_mode == 0) {
      // K=512 over [x_t | h], packed weights
      #pragma unroll 1
      for (int kt = 0; kt < 16; ++kt) {
        bfx8 a;
        if (kt < 8) {
          const floatx4* px =
              (const floatx4*)(x + ((size_t)(b0 + n) * 512 + t) * 256 + kt * 32 + quad * 8);
          floatx4 lo = px[0], hi = px[1];
          a[0] = f2bf(lo[0]); a[1] = f2bf(lo[1]); a[2] = f2bf(lo[2]); a[3] = f2bf(lo[3]);
          a[4] = f2bf(hi[0]); a[5] = f2bf(hi[1]); a[6] = f2bf(hi[2]); a[7] = f2bf(hi[3]);
        } else {
          a = *(const bfx8*)&hA[(n * 256 + (kt - 8) * 32 + quad * 8) ^ ((n & 7) << 3)];
        }
        for (int nt = 0; nt < 8; ++nt) {
          int col = wave * 128 + nt * 16 + n;
          bfx8 bf = *(const bfx8*)(WgP + (size_t)col * 512 + kt * 32 + quad * 8);
          acc[nt] = __builtin_amdgcn_mfma_f32_16x16x32_bf16(a, bf, acc[nt], 0, 0, 0);
        }
      }
    } else {
      // NO workspace: K=512, f32 weights converted on the fly (emergency path)
      #pragma unroll 1
      for (int kt = 0; kt < 16; ++kt) {
        bfx8 a;
        if (kt < 8) {
          const floatx4* px =
              (const floatx4*)(x + ((size_t)(b0 + n) * 512 + t) * 256 + kt * 32 + quad * 8);
          floatx4 lo = px[0], hi = px[1];
          a[0] = f2bf(lo[0]); a[1] = f2bf(lo[1]); a[2] = f2bf(lo[2]); a[3] = f2bf(lo[3]);
          a[4] = f2bf(hi[0]); a[5] = f2bf(hi[1]); a[6] = f2bf(hi[2]); a[7] = f2bf(hi[3]);
        } else {
          a = *(const bfx8*)&hA[(n * 256 + (kt - 8) * 32 + quad * 8) ^ ((n & 7) << 3)];
        }
        for (int nt = 0; nt < 8; ++nt) {
          int col = wave * 128 + nt * 16 + n;
          bfx8 bf;
          #pragma unroll
          for (int j = 0; j < 8; ++j) {
            int k = kt * 32 + quad * 8 + j;
            float v = (k < 256) ? Wih[k * 1024 + col] : Whh[(k - 256) * 1024 + col];
            bf[j] = f2bf(v);
          }
          acc[nt] = __builtin_amdgcn_mfma_f32_16x16x32_bf16(a, bf, acc[nt], 0, 0, 0);
        }
      }
    }
    #pragma unroll
    for (int nt = 0; nt < 8; ++nt)
      #pragma unroll
      for (int r = 0; r < 4; ++r)
        xg[quad * 4 + r][wave * 128 + nt * 16 + n] = acc[nt][r];
    __syncthreads();

    // ---- activations + pre_c / pre_h (cell role) ----
    #pragma unroll
    for (int r = 0; r < 8; ++r) {
      int u = u0 + 32 * r;
      float gi = sigm(xg[bc][u] + xw[0][r]);
      float gf = sigm(xg[bc][256 + u] + xw[1][r]);
      float gg = tanhfast(xg[bc][512 + u] + xw[2][r]);
      float go = sigm(xg[bc][768 + u] + xw[3][r]);
      float co = c_reg[r];
      float pc = gf * co + gi * gg;
      float ph = go * tanhfast(co);  // OLD c
      int si = (bc * 256 + u) ^ ((bc & 7) << 3);
      pA[0][si] = f2bf(ph);
      pA[1][si] = f2bf(pc);
    }
    // prefetch eps for the sampling stage (hidden under phase B)
    float ehv[8], ecv[8];
    {
      const float* pe = eps_h + ((size_t)t * 64 + b0 + bc) * 256;
      const float* pc2 = eps_c + ((size_t)t * 64 + b0 + bc) * 256;
      #pragma unroll
      for (int r = 0; r < 8; ++r) {
        ehv[r] = pe[u0 + 32 * r];
        ecv[r] = pc2[u0 + 32 * r];
      }
    }
    __syncthreads();

    // ---- phase B: reparam GEMMs (waves 0-3: pre_h@Hrep, 4-7: pre_c@Crep) ----
    const short* Asrc = pA[(wave < 4) ? 0 : 1];
    floatx4 racc[8];
    #pragma unroll
    for (int nt = 0; nt < 8; ++nt) racc[nt] = 0.f;
    if (xw_mode >= 0) {
      const short* Rp = (wave < 4) ? HrepP : CrepP;
      #pragma unroll
      for (int kt = 0; kt < 8; ++kt) {
        bfx8 a = *(const bfx8*)&Asrc[(n * 256 + kt * 32 + quad * 8) ^ ((n & 7) << 3)];
        #pragma unroll
        for (int nt = 0; nt < 8; ++nt) {
          int col = (wave & 3) * 128 + nt * 16 + n;
          bfx8 bf = *(const bfx8*)(Rp + (size_t)col * 256 + kt * 32 + quad * 8);
          racc[nt] = __builtin_amdgcn_mfma_f32_16x16x32_bf16(a, bf, racc[nt], 0, 0, 0);
        }
      }
    } else {
      const float* Rf = (wave < 4) ? Hrep : Crep;
      #pragma unroll 1
      for (int kt = 0; kt < 8; ++kt) {
        bfx8 a = *(const bfx8*)&Asrc[(n * 256 + kt * 32 + quad * 8) ^ ((n & 7) << 3)];
        for (int nt = 0; nt < 8; ++nt) {
          int col = (wave & 3) * 128 + nt * 16 + n;
          bfx8 bf;
          #pragma unroll
          for (int j = 0; j < 8; ++j)
            bf[j] = f2bf(Rf[(kt * 32 + quad * 8 + j) * 512 + col]);
          racc[nt] = __builtin_amdgcn_mfma_f32_16x16x32_bf16(a, bf, racc[nt], 0, 0, 0);
        }
      }
    }
    #pragma unroll
    for (int nt = 0; nt < 8; ++nt)
      #pragma unroll
      for (int r = 0; r < 4; ++r)
        xg[quad * 4 + r][wave * 128 + nt * 16 + n] = racc[nt][r];
    __syncthreads();

    // ---- sampling epilogue + outputs (cell role) ----
    #pragma unroll
    for (int r = 0; r < 8; ++r) {
      int u = u0 + 32 * r;
      float mh = fminf(fmaxf(xg[bc][u], 1e-6f), 1e6f);
      float sh = fmaxf(softplusf(xg[bc][256 + u]), 1e-6f);
      float mc = fminf(fmaxf(xg[bc][512 + u], 1e-6f), 1e6f);
      float sc = fmaxf(softplusf(xg[bc][768 + u]), 1e-6f);
      float hn = mh + ehv[r] * sh;
      float cn = mc + ecv[r] * sc;
      c_reg[r] = cn;
      hA[(bc * 256 + u) ^ ((bc & 7) << 3)] = f2bf(hn);
      size_t o = ((size_t)(b0 + bc) * 512 + t) * 256 + u;
      out[o] = hn;
      out[OSTRIDE + o] = cn;
      out[2 * OSTRIDE + o] = mh;
      out[3 * OSTRIDE + o] = sh;
      out[4 * OSTRIDE + o] = mc;
      out[5 * OSTRIDE + o] = sc;
      if (t == 511) {
        out[6 * OSTRIDE + (size_t)(b0 + bc) * 256 + u] = hn;
        out[6 * OSTRIDE + 16384 + (size_t)(b0 + bc) * 256 + u] = cn;
      }
    }
    __syncthreads();  // hA/xg stable before next step's phase A
  }
}

extern "C" void kernel_launch(void* const* d_in, const int* in_sizes, int n_in,
                              void* d_out, int out_size, void* d_ws, size_t ws_size,
                              hipStream_t stream) {
  (void)in_sizes; (void)n_in; (void)out_size;
  const float* x     = (const float*)d_in[0];
  const float* Wih   = (const float*)d_in[1];
  const float* Whh   = (const float*)d_in[2];
  const float* bias  = (const float*)d_in[3];
  const float* Hrep  = (const float*)d_in[4];
  const float* Crep  = (const float*)d_in[5];
  const float* eps_h = (const float*)d_in[6];
  const float* eps_c = (const float*)d_in[7];
  float* out = (float*)d_out;

  char* ws = (char*)d_ws;
  short* WgP   = (short*)ws;                             // 1 MB
  short* HrepP = (short*)(ws + (1 << 20));               // 256 KB
  short* CrepP = (short*)(ws + (1 << 20) + (256 << 10)); // 256 KB
  const size_t need_pack = (1 << 20) + (512 << 10);      // 1.5 MB
  const size_t xw_f32 = (size_t)32768 * 1024 * 4;        // 128 MB
  const size_t xw_b16 = (size_t)32768 * 1024 * 2;        // 64 MB

  int xw_mode;
  float* xwf = nullptr;
  short* xwh = nullptr;
  if (ws_size >= need_pack + xw_f32) {
    xw_mode = 1; xwf = (float*)(ws + need_pack);
  } else if (ws_size >= need_pack + xw_b16) {
    xw_mode = 2; xwh = (short*)(ws + need_pack);
  } else if (ws_size >= need_pack) {
    xw_mode = 0;
  } else {
    xw_mode = -1;  // never touch d_ws at all
  }

  if (xw_mode >= 0)
    pack_kernel<<<dim3(3072), dim3(256), 0, stream>>>(Wih, Whh, Hrep, Crep,
                                                      WgP, HrepP, CrepP);
  if (xw_mode > 0)
    xw_gemm_kernel<<<dim3(512, 4), dim3(256), 0, stream>>>(x, WgP, bias, xwf, xwh,
                                                           xw_mode == 2);
  recur_kernel<<<dim3(4), dim3(512), 0, stream>>>(
      x, WgP, Wih, Whh, bias, HrepP, CrepP, Hrep, Crep,
      eps_h, eps_c, xwf, xwh, xw_mode, out);
}

// Round 4
// 18053.917 us; speedup vs baseline: 1.4335x; 1.4335x over previous
//
#include <hip/hip_runtime.h>
#include <stdint.h>

// Recursive Gaussian LSTM, batch-partitioned, ZERO global barriers,
// ALL recurrent weights register-resident.
// 4 WGs x 16 batches x 1024 threads (16 waves). Each wave owns 64 weight
// columns; Whh + Hrep/Crep B-fragments (bf16) are loaded ONCE into ~256 VGPRs
// per thread, so the 512-step loop performs no weight memory traffic at all
// (round-3 counters showed the per-step L2 weight re-stream was latency-bound
// at 50us/step with only 8 waves/CU to hide it).
// The non-recurrent x@Wih+bias is precomputed by xw_gemm directly into out
// regions 2..5 (mu/std planes, 128 MB): slot (2+g, b, t, u) is read at the top
// of step t by the exact thread that overwrites it with mu/std at the bottom
// of step t -> no extra workspace, no ordering hazard.
// Workspace use: only the optional 1.5 MB bf16 weight pack (gated on ws_size;
// f32 fallback converts on the fly during the one-time init).

#define OSTRIDE 8388608ull  // B*T*HS

typedef float floatx4 __attribute__((ext_vector_type(4)));
typedef short bfx8 __attribute__((ext_vector_type(8)));

__device__ inline short f2bf(float f) {
  union { float f; uint32_t u; } v; v.f = f;
  uint32_t r = v.u + 0x7fffu + ((v.u >> 16) & 1u);  // RNE
  return (short)(r >> 16);
}
__device__ inline float bf2f(short s) {
  union { uint32_t u; float f; } v; v.u = ((uint32_t)(uint16_t)s) << 16;
  return v.f;
}
__device__ inline float sigm(float x) { return 1.f / (1.f + __expf(-x)); }
__device__ inline float tanhfast(float x) {
  float e = __expf(2.f * x);
  return 1.f - 2.f / (e + 1.f);
}
__device__ inline float softplusf(float x) {
  return (x > 15.f) ? x : log1pf(__expf(x));
}

// ---------------- pack weights -> bf16, column-major-K (optional) ------------
// WgP[col][k]: col<1024, k<512 (k<256 from Wih, k>=256 from Whh)
// HrepP/CrepP[col][k]: col<512, k<256
__global__ __launch_bounds__(256)
void pack_kernel(const float* __restrict__ Wih, const float* __restrict__ Whh,
                 const float* __restrict__ Hrep, const float* __restrict__ Crep,
                 short* __restrict__ WgP, short* __restrict__ HrepP,
                 short* __restrict__ CrepP) {
  int idx = blockIdx.x * 256 + threadIdx.x;
  if (idx < 524288) {
    int col = idx >> 9, k = idx & 511;
    float v = (k < 256) ? Wih[k * 1024 + col] : Whh[(k - 256) * 1024 + col];
    WgP[idx] = f2bf(v);
  } else if (idx < 655360) {
    int j = idx - 524288, col = j >> 8, k = j & 255;
    HrepP[j] = f2bf(Hrep[k * 512 + col]);
  } else {
    int j = idx - 655360, col = j >> 8, k = j & 255;
    CrepP[j] = f2bf(Crep[k * 512 + col]);
  }
}

// ---------------- xW = x @ Wih + bias -> out regions 2..5 --------------------
// Slot for (t, b, gate g, unit u): out[(2+g)*OSTRIDE + (b*512 + t)*256 + u].
// Every slot is overwritten with mu/std by the recurrent kernel at step t,
// strictly after the same thread has consumed the xW value.
__global__ __launch_bounds__(256)
void xw_gemm_kernel(const float* __restrict__ x, const short* __restrict__ WgP,
                    const float* __restrict__ Wih, const float* __restrict__ bias,
                    float* __restrict__ out, int packed) {
  const int t  = blockIdx.x;            // 512 time steps (M-tile of 64 batches)
  const int gy = blockIdx.y;            // 4 N-blocks of 256 cols
  const int wave = threadIdx.x >> 6, l = threadIdx.x & 63;
  const int n = l & 15, quad = l >> 4;

  floatx4 acc[4][4];
  #pragma unroll
  for (int mt = 0; mt < 4; ++mt)
    #pragma unroll
    for (int nt = 0; nt < 4; ++nt) acc[mt][nt] = 0.f;

  #pragma unroll
  for (int kt = 0; kt < 8; ++kt) {
    bfx8 a[4];
    #pragma unroll
    for (int mt = 0; mt < 4; ++mt) {
      int b = mt * 16 + n;
      const floatx4* px =
          (const floatx4*)(x + ((size_t)b * 512 + t) * 256 + kt * 32 + quad * 8);
      floatx4 lo = px[0], hi = px[1];
      bfx8 av;
      av[0] = f2bf(lo[0]); av[1] = f2bf(lo[1]); av[2] = f2bf(lo[2]); av[3] = f2bf(lo[3]);
      av[4] = f2bf(hi[0]); av[5] = f2bf(hi[1]); av[6] = f2bf(hi[2]); av[7] = f2bf(hi[3]);
      a[mt] = av;
    }
    #pragma unroll
    for (int nt = 0; nt < 4; ++nt) {
      int col = gy * 256 + wave * 64 + nt * 16 + n;
      bfx8 bf;
      if (packed) {
        bf = *(const bfx8*)(WgP + (size_t)col * 512 + kt * 32 + quad * 8);
      } else {
        #pragma unroll
        for (int j = 0; j < 8; ++j)
          bf[j] = f2bf(Wih[(size_t)(kt * 32 + quad * 8 + j) * 1024 + col]);
      }
      #pragma unroll
      for (int mt = 0; mt < 4; ++mt)
        acc[mt][nt] = __builtin_amdgcn_mfma_f32_16x16x32_bf16(a[mt], bf, acc[mt][nt], 0, 0, 0);
    }
  }
  #pragma unroll
  for (int nt = 0; nt < 4; ++nt) {
    int col = gy * 256 + wave * 64 + nt * 16 + n;
    int g = col >> 8, u = col & 255;
    float bv = bias[col];
    #pragma unroll
    for (int mt = 0; mt < 4; ++mt)
      #pragma unroll
      for (int r = 0; r < 4; ++r) {
        int b = mt * 16 + quad * 4 + r;
        out[(size_t)(2 + g) * OSTRIDE + ((size_t)b * 512 + t) * 256 + u] =
            acc[mt][nt][r] + bv;
      }
  }
}

// ---------------- recurrent kernel: 4 WGs x 16 waves, weights in VGPRs -------
__global__ __launch_bounds__(1024, 4)
void recur_kernel(const short* __restrict__ WgP,
                  const short* __restrict__ HrepP, const short* __restrict__ CrepP,
                  const float* __restrict__ Whh,
                  const float* __restrict__ Hrep, const float* __restrict__ Crep,
                  const float* __restrict__ eps_h, const float* __restrict__ eps_c,
                  float* __restrict__ out, int packed) {
  const int tid = threadIdx.x;
  const int wave = tid >> 6, l = tid & 63;
  const int n = l & 15, quad = l >> 4;     // MFMA roles
  const int b0 = blockIdx.x * 16;          // this WG's batch range
  const int bc = wave;                     // cell role: batch 0..15 (== wave)
  const int u0 = l;                        // cell role: unit = u0 + 64*r

  // LDS: gate/output exchange (f32, stride 1028 breaks power-of-2 conflicts);
  // h(t-1) and pre_h/pre_c as bf16 MFMA-A sources, XOR-swizzled 16B granules
  // (identical formulas to the round-3 PASSING kernel).
  __shared__ float xg[16][1028];     // 65.8 KB
  __shared__ short hA[4096];         // 8 KB
  __shared__ short pA[2][4096];      // 16 KB

  // ---- one-time init: ALL weight B-fragments into registers ----
  // Phase A: wave owns Whh cols [wave*64, wave*64+64)  (K=256)
  // Phase B: waves 0-7 own Hrep cols, waves 8-15 own Crep cols (64 each)
  bfx8 BW[4][8];
  bfx8 BR[4][8];
  #pragma unroll
  for (int nt = 0; nt < 4; ++nt) {
    const int colA = wave * 64 + nt * 16 + n;
    const int colR = (wave & 7) * 64 + nt * 16 + n;
    #pragma unroll
    for (int kt = 0; kt < 8; ++kt) {
      if (packed) {
        BW[nt][kt] = *(const bfx8*)(WgP + (size_t)colA * 512 + 256 + kt * 32 + quad * 8);
        const short* Rp = (wave < 8) ? HrepP : CrepP;
        BR[nt][kt] = *(const bfx8*)(Rp + (size_t)colR * 256 + kt * 32 + quad * 8);
      } else {
        const float* Rf = (wave < 8) ? Hrep : Crep;
        bfx8 w, r;
        #pragma unroll
        for (int j = 0; j < 8; ++j) {
          int k = kt * 32 + quad * 8 + j;
          w[j] = f2bf(Whh[(size_t)k * 1024 + colA]);
          r[j] = f2bf(Rf[(size_t)k * 512 + colR]);
        }
        BW[nt][kt] = w;
        BR[nt][kt] = r;
      }
    }
  }

  for (int i = tid; i < 4096; i += 1024) hA[i] = 0;
  float c_reg[4] = {0.f, 0.f, 0.f, 0.f};
  __syncthreads();

  #pragma unroll 1
  for (int t = 0; t < 512; ++t) {
    // ---- prefetch xW (from out regions 2..5) + eps (cell role) ----
    float xw[4][4], ehv[4], ecv[4];
    #pragma unroll
    for (int g = 0; g < 4; ++g)
      #pragma unroll
      for (int r = 0; r < 4; ++r)
        xw[g][r] = out[(size_t)(2 + g) * OSTRIDE +
                       ((size_t)(b0 + bc) * 512 + t) * 256 + u0 + 64 * r];
    #pragma unroll
    for (int r = 0; r < 4; ++r) {
      ehv[r] = eps_h[((size_t)t * 64 + b0 + bc) * 256 + u0 + 64 * r];
      ecv[r] = eps_c[((size_t)t * 64 + b0 + bc) * 256 + u0 + 64 * r];
    }

    // ---- phase A: h(t-1) @ Whh, weights from registers ----
    floatx4 acc[4];
    #pragma unroll
    for (int nt = 0; nt < 4; ++nt) acc[nt] = 0.f;
    #pragma unroll
    for (int kt = 0; kt < 8; ++kt) {
      bfx8 a = *(const bfx8*)&hA[(n * 256 + kt * 32 + quad * 8) ^ ((n & 7) << 3)];
      #pragma unroll
      for (int nt = 0; nt < 4; ++nt)
        acc[nt] = __builtin_amdgcn_mfma_f32_16x16x32_bf16(a, BW[nt][kt], acc[nt], 0, 0, 0);
    }
    #pragma unroll
    for (int nt = 0; nt < 4; ++nt)
      #pragma unroll
      for (int r = 0; r < 4; ++r)
        xg[quad * 4 + r][wave * 64 + nt * 16 + n] = acc[nt][r];
    __syncthreads();

    // ---- activations + pre_c / pre_h (cell role) ----
    #pragma unroll
    for (int r = 0; r < 4; ++r) {
      int u = u0 + 64 * r;
      float gi = sigm(xg[bc][u] + xw[0][r]);
      float gf = sigm(xg[bc][256 + u] + xw[1][r]);
      float gg = tanhfast(xg[bc][512 + u] + xw[2][r]);
      float go = sigm(xg[bc][768 + u] + xw[3][r]);
      float co = c_reg[r];
      float pc = gf * co + gi * gg;
      float ph = go * tanhfast(co);  // OLD c
      int si = (bc * 256 + u) ^ ((bc & 7) << 3);
      pA[0][si] = f2bf(ph);
      pA[1][si] = f2bf(pc);
    }
    __syncthreads();

    // ---- phase B: reparam GEMMs, weights from registers ----
    const short* Asrc = pA[(wave < 8) ? 0 : 1];
    floatx4 racc[4];
    #pragma unroll
    for (int nt = 0; nt < 4; ++nt) racc[nt] = 0.f;
    #pragma unroll
    for (int kt = 0; kt < 8; ++kt) {
      bfx8 a = *(const bfx8*)&Asrc[(n * 256 + kt * 32 + quad * 8) ^ ((n & 7) << 3)];
      #pragma unroll
      for (int nt = 0; nt < 4; ++nt)
        racc[nt] = __builtin_amdgcn_mfma_f32_16x16x32_bf16(a, BR[nt][kt], racc[nt], 0, 0, 0);
    }
    // Hrep col c -> xg col c (h_mu/h_std); Crep col c -> xg col 512+c
    #pragma unroll
    for (int nt = 0; nt < 4; ++nt)
      #pragma unroll
      for (int r = 0; r < 4; ++r)
        xg[quad * 4 + r][((wave < 8) ? 0 : 512) + (wave & 7) * 64 + nt * 16 + n] =
            racc[nt][r];
    __syncthreads();

    // ---- sampling epilogue + outputs (cell role) ----
    #pragma unroll
    for (int r = 0; r < 4; ++r) {
      int u = u0 + 64 * r;
      float mh = fminf(fmaxf(xg[bc][u], 1e-6f), 1e6f);
      float sh = fmaxf(softplusf(xg[bc][256 + u]), 1e-6f);
      float mc = fminf(fmaxf(xg[bc][512 + u], 1e-6f), 1e6f);
      float sc = fmaxf(softplusf(xg[bc][768 + u]), 1e-6f);
      float hn = mh + ehv[r] * sh;
      float cn = mc + ecv[r] * sc;
      c_reg[r] = cn;
      hA[(bc * 256 + u) ^ ((bc & 7) << 3)] = f2bf(hn);
      size_t o = ((size_t)(b0 + bc) * 512 + t) * 256 + u;
      out[o] = hn;
      out[OSTRIDE + o] = cn;
      out[2 * OSTRIDE + o] = mh;
      out[3 * OSTRIDE + o] = sh;
      out[4 * OSTRIDE + o] = mc;
      out[5 * OSTRIDE + o] = sc;
      if (t == 511) {
        out[6 * OSTRIDE + (size_t)(b0 + bc) * 256 + u] = hn;
        out[6 * OSTRIDE + 16384 + (size_t)(b0 + bc) * 256 + u] = cn;
      }
    }
    __syncthreads();  // hA/xg stable before next step's phase A
  }
}

extern "C" void kernel_launch(void* const* d_in, const int* in_sizes, int n_in,
                              void* d_out, int out_size, void* d_ws, size_t ws_size,
                              hipStream_t stream) {
  (void)in_sizes; (void)n_in; (void)out_size;
  const float* x     = (const float*)d_in[0];
  const float* Wih   = (const float*)d_in[1];
  const float* Whh   = (const float*)d_in[2];
  const float* bias  = (const float*)d_in[3];
  const float* Hrep  = (const float*)d_in[4];
  const float* Crep  = (const float*)d_in[5];
  const float* eps_h = (const float*)d_in[6];
  const float* eps_c = (const float*)d_in[7];
  float* out = (float*)d_out;

  char* ws = (char*)d_ws;
  short* WgP   = (short*)ws;                             // 1 MB
  short* HrepP = (short*)(ws + (1 << 20));               // 256 KB
  short* CrepP = (short*)(ws + (1 << 20) + (256 << 10)); // 256 KB
  const size_t need_pack = (1 << 20) + (512 << 10);      // 1.5 MB
  const int packed = (ws_size >= need_pack) ? 1 : 0;

  if (packed)
    pack_kernel<<<dim3(3072), dim3(256), 0, stream>>>(Wih, Whh, Hrep, Crep,
                                                      WgP, HrepP, CrepP);
  xw_gemm_kernel<<<dim3(512, 4), dim3(256), 0, stream>>>(x, WgP, Wih, bias,
                                                         out, packed);
  recur_kernel<<<dim3(4), dim3(1024), 0, stream>>>(
      WgP, HrepP, CrepP, Whh, Hrep, Crep, eps_h, eps_c, out, packed);
}

// Round 6
// 8525.340 us; speedup vs baseline: 3.0356x; 2.1177x over previous
//
#include <hip/hip_runtime.h>
#include <stdint.h>

// Recursive Gaussian LSTM. 16 WGs = 4 batch-groups x 4 WGs; each WG owns 64
// units (all 4 gates + all 4 reparam outputs for those units) of its group's
// 16 batches. ALL weights are TRULY register-resident: 128 VGPRs/thread of
// bf16 B-fragments under a 256-VGPR cap (launch_bounds(512,2)) -- round 4
// proved (VGPR_Count=64) that a 128-cap config silently spills weights to
// scratch and serializes on ~200cy reloads. Two intra-group exchanges per
// step (pre_h/pre_c, then h) via L2/LLC global buffers with the round-0-
// proven release/acquire flag barrier, among 4 WGs only.
// x@Wih+bias is precomputed into out planes 2..5 (read at step-top by the
// same thread that overwrites the slot with mu/std at step-bottom).

#define OSTRIDE 8388608ull  // B*T*HS

typedef float floatx4 __attribute__((ext_vector_type(4)));
typedef short bfx8 __attribute__((ext_vector_type(8)));

__device__ inline short f2bf(float f) {
  union { float f; uint32_t u; } v; v.f = f;
  uint32_t r = v.u + 0x7fffu + ((v.u >> 16) & 1u);  // RNE
  return (short)(r >> 16);
}
__device__ inline float bf2f(short s) {
  union { uint32_t u; float f; } v; v.u = ((uint32_t)(uint16_t)s) << 16;
  return v.f;
}
__device__ inline float sigm(float x) { return 1.f / (1.f + __expf(-x)); }
__device__ inline float tanhfast(float x) {
  float e = __expf(2.f * x);
  return 1.f - 2.f / (e + 1.f);
}
__device__ inline float softplusf(float x) {
  return (x > 15.f) ? x : log1pf(__expf(x));
}

// ---------------- pack weights -> bf16, column-major-K (optional) ------------
__global__ __launch_bounds__(256)
void pack_kernel(const float* __restrict__ Wih, const float* __restrict__ Whh,
                 const float* __restrict__ Hrep, const float* __restrict__ Crep,
                 short* __restrict__ WgP, short* __restrict__ HrepP,
                 short* __restrict__ CrepP) {
  int idx = blockIdx.x * 256 + threadIdx.x;
  if (idx < 524288) {
    int col = idx >> 9, k = idx & 511;
    float v = (k < 256) ? Wih[k * 1024 + col] : Whh[(k - 256) * 1024 + col];
    WgP[idx] = f2bf(v);
  } else if (idx < 655360) {
    int j = idx - 524288, col = j >> 8, k = j & 255;
    HrepP[j] = f2bf(Hrep[k * 512 + col]);
  } else {
    int j = idx - 655360, col = j >> 8, k = j & 255;
    CrepP[j] = f2bf(Crep[k * 512 + col]);
  }
}

// ---------------- xW = x @ Wih + bias -> out planes 2..5 ---------------------
__global__ __launch_bounds__(256)
void xw_gemm_kernel(const float* __restrict__ x, const short* __restrict__ WgP,
                    const float* __restrict__ Wih, const float* __restrict__ bias,
                    float* __restrict__ out, int packed) {
  const int t  = blockIdx.x;            // 512 time steps (M-tile = 64 batches)
  const int gy = blockIdx.y;            // 4 N-blocks of 256 cols
  const int wave = threadIdx.x >> 6, l = threadIdx.x & 63;
  const int n = l & 15, quad = l >> 4;

  floatx4 acc[4][4];
  #pragma unroll
  for (int mt = 0; mt < 4; ++mt)
    #pragma unroll
    for (int nt = 0; nt < 4; ++nt) acc[mt][nt] = 0.f;

  #pragma unroll
  for (int kt = 0; kt < 8; ++kt) {
    bfx8 a[4];
    #pragma unroll
    for (int mt = 0; mt < 4; ++mt) {
      int b = mt * 16 + n;
      const floatx4* px =
          (const floatx4*)(x + ((size_t)b * 512 + t) * 256 + kt * 32 + quad * 8);
      floatx4 lo = px[0], hi = px[1];
      bfx8 av;
      av[0] = f2bf(lo[0]); av[1] = f2bf(lo[1]); av[2] = f2bf(lo[2]); av[3] = f2bf(lo[3]);
      av[4] = f2bf(hi[0]); av[5] = f2bf(hi[1]); av[6] = f2bf(hi[2]); av[7] = f2bf(hi[3]);
      a[mt] = av;
    }
    #pragma unroll
    for (int nt = 0; nt < 4; ++nt) {
      int col = gy * 256 + wave * 64 + nt * 16 + n;
      bfx8 bf;
      if (packed) {
        bf = *(const bfx8*)(WgP + (size_t)col * 512 + kt * 32 + quad * 8);
      } else {
        #pragma unroll
        for (int j = 0; j < 8; ++j)
          bf[j] = f2bf(Wih[(size_t)(kt * 32 + quad * 8 + j) * 1024 + col]);
      }
      #pragma unroll
      for (int mt = 0; mt < 4; ++mt)
        acc[mt][nt] = __builtin_amdgcn_mfma_f32_16x16x32_bf16(a[mt], bf, acc[mt][nt], 0, 0, 0);
    }
  }
  #pragma unroll
  for (int nt = 0; nt < 4; ++nt) {
    int col = gy * 256 + wave * 64 + nt * 16 + n;
    int g = col >> 8, u = col & 255;
    float bv = bias[col];
    #pragma unroll
    for (int mt = 0; mt < 4; ++mt)
      #pragma unroll
      for (int r = 0; r < 4; ++r) {
        int b = mt * 16 + quad * 4 + r;
        out[(size_t)(2 + g) * OSTRIDE + ((size_t)b * 512 + t) * 256 + u] =
            acc[mt][nt][r] + bv;
      }
  }
}

// ---- 4-WG group barrier: release own flag, wave0 spins on the 4 members ----
__device__ inline void gbar4(int* flags, int g, int bx, int ep) {
  __threadfence();   // make this WG's global writes visible at agent scope
  __syncthreads();
  if (threadIdx.x == 0)
    __hip_atomic_store(flags + bx * 16, ep, __ATOMIC_RELEASE, __HIP_MEMORY_SCOPE_AGENT);
  if (threadIdx.x < 64) {
    int peer = g + ((threadIdx.x & 3) << 2);   // group g = blocks {g, g+4, g+8, g+12}
    int v;
    do {
      v = __hip_atomic_load(flags + peer * 16, __ATOMIC_ACQUIRE, __HIP_MEMORY_SCOPE_AGENT);
      if (v < ep) __builtin_amdgcn_s_sleep(1);
    } while (__any(v < ep));
  }
  __syncthreads();
  __threadfence();   // acquire for all threads of the WG
}

// ---------------- recurrent kernel: 16 WGs, weights truly in VGPRs ----------
__global__ __launch_bounds__(512, 2)
void recur_kernel(const short* __restrict__ WgP,
                  const short* __restrict__ HrepP, const short* __restrict__ CrepP,
                  const float* __restrict__ Whh,
                  const float* __restrict__ Hrep, const float* __restrict__ Crep,
                  const float* __restrict__ eps_h, const float* __restrict__ eps_c,
                  float* __restrict__ out,
                  int* __restrict__ flags, short* __restrict__ preX,
                  short* __restrict__ htX, int packed) {
  const int tid = threadIdx.x;
  const int w = tid >> 6, l = tid & 63;
  const int n = l & 15, quad = l >> 4;     // MFMA roles
  const int bx = blockIdx.x;
  const int g = bx & 3, q = bx >> 2;       // batch-group, unit-quarter
  const int B0 = g * 16;                   // group's batch base
  const int bc = tid >> 5;                 // cell role: batch 0..15
  const int v0 = tid & 31;                 // cell role: units v0, v0+32
  const int U0 = q * 64;                   // this WG's unit base

  __shared__ float xg[16][260];      // 16.3 KB gate/output exchange (pad 4)
  __shared__ short hA[4096];         // 8 KB  full h(t-1), swizzled bf16
  __shared__ short pA[2][4096];      // 16 KB full pre_h/pre_c, swizzled bf16

  // ---- one-time init: weight B-fragments -> registers (128 VGPRs) ----
  // Phase A: local gate-col c = w*32+nt*16+n in [0,256): gate gt=c>>6,
  //          unit v=c&63 -> Whh col gt*256 + U0 + v.
  // Phase B: waves 0-3 Hrep, 4-7 Crep; local c2=(w&3)*32+nt*16+n in [0,128):
  //          col = (c2>>6)*256 + U0 + (c2&63)  (mu half then std half).
  bfx8 BW[2][8], BR[2][8];
  #pragma unroll
  for (int nt = 0; nt < 2; ++nt) {
    const int c    = w * 32 + nt * 16 + n;
    const int colW = (c >> 6) * 256 + U0 + (c & 63);
    const int c2   = (w & 3) * 32 + nt * 16 + n;
    const int colR = (c2 >> 6) * 256 + U0 + (c2 & 63);
    #pragma unroll
    for (int kt = 0; kt < 8; ++kt) {
      if (packed) {
        BW[nt][kt] = *(const bfx8*)(WgP + (size_t)colW * 512 + 256 + kt * 32 + quad * 8);
        const short* Rp = (w < 4) ? HrepP : CrepP;
        BR[nt][kt] = *(const bfx8*)(Rp + (size_t)colR * 256 + kt * 32 + quad * 8);
      } else {
        const float* Rf = (w < 4) ? Hrep : Crep;
        bfx8 bw, br;
        #pragma unroll
        for (int j = 0; j < 8; ++j) {
          int k = kt * 32 + quad * 8 + j;
          bw[j] = f2bf(Whh[(size_t)k * 1024 + colW]);
          br[j] = f2bf(Rf[(size_t)k * 512 + colR]);
        }
        BW[nt][kt] = bw; BR[nt][kt] = br;
      }
    }
  }

  for (int i = tid; i < 4096; i += 512) hA[i] = 0;
  float c_reg[2] = {0.f, 0.f};
  __syncthreads();

  #pragma unroll 1
  for (int t = 0; t < 512; ++t) {
    // ---- prefetch xW (out planes 2..5) + eps; consumed after phase A ----
    float xw[4][2], ehv[2], ecv[2];
    #pragma unroll
    for (int gt = 0; gt < 4; ++gt)
      #pragma unroll
      for (int cl = 0; cl < 2; ++cl)
        xw[gt][cl] = out[(size_t)(2 + gt) * OSTRIDE +
                         ((size_t)(B0 + bc) * 512 + t) * 256 + U0 + v0 + 32 * cl];
    #pragma unroll
    for (int cl = 0; cl < 2; ++cl) {
      ehv[cl] = eps_h[((size_t)t * 64 + B0 + bc) * 256 + U0 + v0 + 32 * cl];
      ecv[cl] = eps_c[((size_t)t * 64 + B0 + bc) * 256 + U0 + v0 + 32 * cl];
    }

    // ---- phase A: h(t-1) @ Whh (own 256 gate cols), weights in regs ----
    floatx4 acc0 = 0.f, acc1 = 0.f;
    #pragma unroll
    for (int kt = 0; kt < 8; ++kt) {
      bfx8 a = *(const bfx8*)&hA[(n * 256 + kt * 32 + quad * 8) ^ ((n & 7) << 3)];
      acc0 = __builtin_amdgcn_mfma_f32_16x16x32_bf16(a, BW[0][kt], acc0, 0, 0, 0);
      acc1 = __builtin_amdgcn_mfma_f32_16x16x32_bf16(a, BW[1][kt], acc1, 0, 0, 0);
    }
    #pragma unroll
    for (int r = 0; r < 4; ++r) {
      xg[quad * 4 + r][w * 32 + n]      = acc0[r];
      xg[quad * 4 + r][w * 32 + 16 + n] = acc1[r];
    }
    __syncthreads();

    // ---- activations + pre_c/pre_h (cell role); publish to group ----
    #pragma unroll
    for (int cl = 0; cl < 2; ++cl) {
      int v = v0 + 32 * cl, u = U0 + v;
      float gi = sigm(xg[bc][v]        + xw[0][cl]);
      float gf = sigm(xg[bc][64 + v]   + xw[1][cl]);
      float gg = tanhfast(xg[bc][128 + v] + xw[2][cl]);
      float go = sigm(xg[bc][192 + v]  + xw[3][cl]);
      float co = c_reg[cl];
      float pc = gf * co + gi * gg;
      float ph = go * tanhfast(co);  // OLD c
      preX[((size_t)(g * 2)     * 16 + bc) * 256 + u] = f2bf(ph);
      preX[((size_t)(g * 2 + 1) * 16 + bc) * 256 + u] = f2bf(pc);
    }
    gbar4(flags, g, bx, 2 * t + 1);

    // ---- gather full pre_h/pre_c into swizzled LDS ----
    #pragma unroll
    for (int j = 0; j < 2; ++j) {
      int f = (tid + 512 * j) * 8;               // short index in [0,8192)
      int buf = f >> 12, rem = f & 4095, b = rem >> 8, uu = rem & 255;
      bfx8 d = *(const bfx8*)(preX + (size_t)(g * 2 + buf) * 4096 + rem);
      *(bfx8*)&pA[buf][(b * 256 + uu) ^ ((b & 7) << 3)] = d;
    }
    __syncthreads();

    // ---- phase B: reparam (own 256 cols), weights in regs ----
    const short* Asrc = pA[(w < 4) ? 0 : 1];
    floatx4 racc0 = 0.f, racc1 = 0.f;
    #pragma unroll
    for (int kt = 0; kt < 8; ++kt) {
      bfx8 a = *(const bfx8*)&Asrc[(n * 256 + kt * 32 + quad * 8) ^ ((n & 7) << 3)];
      racc0 = __builtin_amdgcn_mfma_f32_16x16x32_bf16(a, BR[0][kt], racc0, 0, 0, 0);
      racc1 = __builtin_amdgcn_mfma_f32_16x16x32_bf16(a, BR[1][kt], racc1, 0, 0, 0);
    }
    {
      int cb = ((w < 4) ? 0 : 128) + (w & 3) * 32;  // mu_h|std_h|mu_c|std_c layout
      #pragma unroll
      for (int r = 0; r < 4; ++r) {
        xg[quad * 4 + r][cb + n]      = racc0[r];
        xg[quad * 4 + r][cb + 16 + n] = racc1[r];
      }
    }
    __syncthreads();

    // ---- sampling epilogue + outputs (cell role); publish h ----
    #pragma unroll
    for (int cl = 0; cl < 2; ++cl) {
      int v = v0 + 32 * cl, u = U0 + v;
      float mh = fminf(fmaxf(xg[bc][v], 1e-6f), 1e6f);
      float sh = fmaxf(softplusf(xg[bc][64 + v]), 1e-6f);
      float mc = fminf(fmaxf(xg[bc][128 + v], 1e-6f), 1e6f);
      float sc = fmaxf(softplusf(xg[bc][192 + v]), 1e-6f);
      float hn = mh + ehv[cl] * sh;
      float cn = mc + ecv[cl] * sc;
      c_reg[cl] = cn;
      htX[(size_t)g * 4096 + bc * 256 + u] = f2bf(hn);
      size_t o = ((size_t)(B0 + bc) * 512 + t) * 256 + u;
      out[o] = hn;
      out[OSTRIDE + o] = cn;
      out[2 * OSTRIDE + o] = mh;
      out[3 * OSTRIDE + o] = sh;
      out[4 * OSTRIDE + o] = mc;
      out[5 * OSTRIDE + o] = sc;
      if (t == 511) {
        out[6 * OSTRIDE + (size_t)(B0 + bc) * 256 + u] = hn;
        out[6 * OSTRIDE + 16384 + (size_t)(B0 + bc) * 256 + u] = cn;
      }
    }
    gbar4(flags, g, bx, 2 * t + 2);

    // ---- gather full h(t) into swizzled LDS for next phase A ----
    {
      int f = tid * 8;                           // short index in [0,4096)
      int b = f >> 8, uu = f & 255;
      *(bfx8*)&hA[(b * 256 + uu) ^ ((b & 7) << 3)] =
          *(const bfx8*)(htX + (size_t)g * 4096 + f);
    }
    __syncthreads();
  }
}

extern "C" void kernel_launch(void* const* d_in, const int* in_sizes, int n_in,
                              void* d_out, int out_size, void* d_ws, size_t ws_size,
                              hipStream_t stream) {
  (void)in_sizes; (void)n_in; (void)out_size;
  const float* x     = (const float*)d_in[0];
  const float* Wih   = (const float*)d_in[1];
  const float* Whh   = (const float*)d_in[2];
  const float* bias  = (const float*)d_in[3];
  const float* Hrep  = (const float*)d_in[4];
  const float* Crep  = (const float*)d_in[5];
  const float* eps_h = (const float*)d_in[6];
  const float* eps_c = (const float*)d_in[7];
  float* out = (float*)d_out;

  char* ws = (char*)d_ws;
  int*   flags = (int*)ws;                         // 1 KB (memset 4 KB)
  short* preX  = (short*)(ws + 4096);              // 64 KB: [4g][2][16][256] bf16
  short* htX   = (short*)(ws + 4096 + 65536);      // 32 KB: [4g][16][256] bf16
  const size_t packoff = 114688;                   // 112 KB
  short* WgP   = (short*)(ws + packoff);                             // 1 MB
  short* HrepP = (short*)(ws + packoff + (1 << 20));                 // 256 KB
  short* CrepP = (short*)(ws + packoff + (1 << 20) + (256 << 10));   // 256 KB
  const int packed = (ws_size >= packoff + (1 << 20) + (512 << 10)) ? 1 : 0;

  hipMemsetAsync(ws, 0, 4096, stream);  // reset barrier flags (capture-proven)
  if (packed)
    pack_kernel<<<dim3(3072), dim3(256), 0, stream>>>(Wih, Whh, Hrep, Crep,
                                                      WgP, HrepP, CrepP);
  xw_gemm_kernel<<<dim3(512, 4), dim3(256), 0, stream>>>(x, WgP, Wih, bias,
                                                         out, packed);
  recur_kernel<<<dim3(16), dim3(512), 0, stream>>>(
      WgP, HrepP, CrepP, Whh, Hrep, Crep, eps_h, eps_c, out,
      flags, preX, htX, packed);
}

// Round 8
// 8378.935 us; speedup vs baseline: 3.0886x; 1.0175x over previous
//
#include <hip/hip_runtime.h>
#include <stdint.h>

// Recursive Gaussian LSTM. 16 WGs = 4 batch-groups x 4 WGs; each WG owns 64
// units of its group's 16 batches. This is the round-6 PASSING kernel (8.5ms)
// with exactly ONE functional change: weight-fragment init loads are VOLATILE,
// so the compiler cannot rematerialize them (round-6 counters: VGPR_Count=120
// < the 128 VGPRs the weight set needs => it was re-streaming ~512KB/WG/step
// from a fence-invalidated L2 instead of keeping weights register-resident).
// Volatile forces one load; with launch_bounds(512,2) => 256-VGPR budget and
// ~200 needed, the allocator keeps them in VGPRs. Output-plane stores gain a
// nontemporal hint (correctness-neutral) to keep L2 clean for the fences.
// Exchange protocol, barrier (threadfence release/acquire), all index math:
// byte-identical to round 6.

#define OSTRIDE 8388608ull  // B*T*HS

typedef float floatx4 __attribute__((ext_vector_type(4)));
typedef short bfx8 __attribute__((ext_vector_type(8)));

__device__ inline short f2bf(float f) {
  union { float f; uint32_t u; } v; v.f = f;
  uint32_t r = v.u + 0x7fffu + ((v.u >> 16) & 1u);  // RNE
  return (short)(r >> 16);
}
__device__ inline float sigm(float x) { return 1.f / (1.f + __expf(-x)); }
__device__ inline float tanhfast(float x) {
  float e = __expf(2.f * x);
  return 1.f - 2.f / (e + 1.f);
}
__device__ inline float softplusf(float x) {
  return (x > 15.f) ? x : log1pf(__expf(x));
}
__device__ inline void ntst(float v, float* p) {
  __builtin_nontemporal_store(v, p);
}

// ---------------- pack weights -> bf16, column-major-K (optional) ------------
__global__ __launch_bounds__(256)
void pack_kernel(const float* __restrict__ Wih, const float* __restrict__ Whh,
                 const float* __restrict__ Hrep, const float* __restrict__ Crep,
                 short* __restrict__ WgP, short* __restrict__ HrepP,
                 short* __restrict__ CrepP) {
  int idx = blockIdx.x * 256 + threadIdx.x;
  if (idx < 524288) {
    int col = idx >> 9, k = idx & 511;
    float v = (k < 256) ? Wih[k * 1024 + col] : Whh[(k - 256) * 1024 + col];
    WgP[idx] = f2bf(v);
  } else if (idx < 655360) {
    int j = idx - 524288, col = j >> 8, k = j & 255;
    HrepP[j] = f2bf(Hrep[k * 512 + col]);
  } else {
    int j = idx - 655360, col = j >> 8, k = j & 255;
    CrepP[j] = f2bf(Crep[k * 512 + col]);
  }
}

// ---------------- xW = x @ Wih + bias -> out planes 2..5 ---------------------
__global__ __launch_bounds__(256)
void xw_gemm_kernel(const float* __restrict__ x, const short* __restrict__ WgP,
                    const float* __restrict__ Wih, const float* __restrict__ bias,
                    float* __restrict__ out, int packed) {
  const int t  = blockIdx.x;            // 512 time steps (M-tile = 64 batches)
  const int gy = blockIdx.y;            // 4 N-blocks of 256 cols
  const int wave = threadIdx.x >> 6, l = threadIdx.x & 63;
  const int n = l & 15, quad = l >> 4;

  floatx4 acc[4][4];
  #pragma unroll
  for (int mt = 0; mt < 4; ++mt)
    #pragma unroll
    for (int nt = 0; nt < 4; ++nt) acc[mt][nt] = 0.f;

  #pragma unroll
  for (int kt = 0; kt < 8; ++kt) {
    bfx8 a[4];
    #pragma unroll
    for (int mt = 0; mt < 4; ++mt) {
      int b = mt * 16 + n;
      const floatx4* px =
          (const floatx4*)(x + ((size_t)b * 512 + t) * 256 + kt * 32 + quad * 8);
      floatx4 lo = px[0], hi = px[1];
      bfx8 av;
      av[0] = f2bf(lo[0]); av[1] = f2bf(lo[1]); av[2] = f2bf(lo[2]); av[3] = f2bf(lo[3]);
      av[4] = f2bf(hi[0]); av[5] = f2bf(hi[1]); av[6] = f2bf(hi[2]); av[7] = f2bf(hi[3]);
      a[mt] = av;
    }
    #pragma unroll
    for (int nt = 0; nt < 4; ++nt) {
      int col = gy * 256 + wave * 64 + nt * 16 + n;
      bfx8 bf;
      if (packed) {
        bf = *(const bfx8*)(WgP + (size_t)col * 512 + kt * 32 + quad * 8);
      } else {
        #pragma unroll
        for (int j = 0; j < 8; ++j)
          bf[j] = f2bf(Wih[(size_t)(kt * 32 + quad * 8 + j) * 1024 + col]);
      }
      #pragma unroll
      for (int mt = 0; mt < 4; ++mt)
        acc[mt][nt] = __builtin_amdgcn_mfma_f32_16x16x32_bf16(a[mt], bf, acc[mt][nt], 0, 0, 0);
    }
  }
  #pragma unroll
  for (int nt = 0; nt < 4; ++nt) {
    int col = gy * 256 + wave * 64 + nt * 16 + n;
    int g = col >> 8, u = col & 255;
    float bv = bias[col];
    #pragma unroll
    for (int mt = 0; mt < 4; ++mt)
      #pragma unroll
      for (int r = 0; r < 4; ++r) {
        int b = mt * 16 + quad * 4 + r;
        out[(size_t)(2 + g) * OSTRIDE + ((size_t)b * 512 + t) * 256 + u] =
            acc[mt][nt][r] + bv;
      }
  }
}

// ---- 4-WG group barrier: release own flag, wave0 spins on the 4 members ----
// (round-0/round-6 proven protocol, unchanged)
__device__ inline void gbar4(int* flags, int g, int bx, int ep) {
  __threadfence();   // make this WG's global writes visible at agent scope
  __syncthreads();
  if (threadIdx.x == 0)
    __hip_atomic_store(flags + bx * 16, ep, __ATOMIC_RELEASE, __HIP_MEMORY_SCOPE_AGENT);
  if (threadIdx.x < 64) {
    int peer = g + ((threadIdx.x & 3) << 2);   // group g = blocks {g,g+4,g+8,g+12}
    int v;
    do {
      v = __hip_atomic_load(flags + peer * 16, __ATOMIC_ACQUIRE, __HIP_MEMORY_SCOPE_AGENT);
      if (v < ep) __builtin_amdgcn_s_sleep(1);
    } while (__any(v < ep));
  }
  __syncthreads();
  __threadfence();   // acquire for all threads of the WG
}

// ---------------- recurrent kernel: 16 WGs, weights pinned via volatile -----
__global__ __launch_bounds__(512, 2)
void recur_kernel(const short* __restrict__ WgP,
                  const short* __restrict__ HrepP, const short* __restrict__ CrepP,
                  const float* __restrict__ Whh,
                  const float* __restrict__ Hrep, const float* __restrict__ Crep,
                  const float* __restrict__ eps_h, const float* __restrict__ eps_c,
                  float* __restrict__ out,
                  int* __restrict__ flags, short* __restrict__ preX,
                  short* __restrict__ htX, int packed) {
  const int tid = threadIdx.x;
  const int w = tid >> 6, l = tid & 63;
  const int n = l & 15, quad = l >> 4;     // MFMA roles
  const int bx = blockIdx.x;
  const int g = bx & 3, q = bx >> 2;       // batch-group, unit-quarter
  const int B0 = g * 16;                   // group's batch base
  const int bc = tid >> 5;                 // cell role: batch 0..15
  const int v0 = tid & 31;                 // cell role: units v0, v0+32
  const int U0 = q * 64;                   // this WG's unit base

  __shared__ float xg[16][260];      // 16.3 KB gate/output exchange (pad 4)
  __shared__ short hA[4096];         // 8 KB  full h(t-1), swizzled bf16
  __shared__ short pA[2][4096];      // 16 KB full pre_h/pre_c, swizzled bf16

  // ---- one-time init: weight B-fragments -> registers (128 VGPRs) ----
  // VOLATILE loads: cannot be rematerialized, so the values must stay live
  // in VGPRs across the whole 512-step loop (budget 256, need ~200).
  bfx8 BW[2][8], BR[2][8];
  #pragma unroll
  for (int nt = 0; nt < 2; ++nt) {
    const int c    = w * 32 + nt * 16 + n;
    const int colW = (c >> 6) * 256 + U0 + (c & 63);
    const int c2   = (w & 3) * 32 + nt * 16 + n;
    const int colR = (c2 >> 6) * 256 + U0 + (c2 & 63);
    #pragma unroll
    for (int kt = 0; kt < 8; ++kt) {
      if (packed) {
        BW[nt][kt] = *(const volatile bfx8*)(WgP + (size_t)colW * 512 + 256 + kt * 32 + quad * 8);
        const short* Rp = (w < 4) ? HrepP : CrepP;
        BR[nt][kt] = *(const volatile bfx8*)(Rp + (size_t)colR * 256 + kt * 32 + quad * 8);
      } else {
        const float* Rf = (w < 4) ? Hrep : Crep;
        bfx8 bw, br;
        #pragma unroll
        for (int j = 0; j < 8; ++j) {
          int k = kt * 32 + quad * 8 + j;
          bw[j] = f2bf(*(const volatile float*)(Whh + (size_t)k * 1024 + colW));
          br[j] = f2bf(*(const volatile float*)(Rf + (size_t)k * 512 + colR));
        }
        BW[nt][kt] = bw; BR[nt][kt] = br;
      }
    }
  }

  for (int i = tid; i < 4096; i += 512) hA[i] = 0;
  float c_reg[2] = {0.f, 0.f};
  __syncthreads();

  #pragma unroll 1
  for (int t = 0; t < 512; ++t) {
    // ---- prefetch xW (out planes 2..5) + eps; consumed after phase A ----
    float xw[4][2], ehv[2], ecv[2];
    #pragma unroll
    for (int gt = 0; gt < 4; ++gt)
      #pragma unroll
      for (int cl = 0; cl < 2; ++cl)
        xw[gt][cl] = out[(size_t)(2 + gt) * OSTRIDE +
                         ((size_t)(B0 + bc) * 512 + t) * 256 + U0 + v0 + 32 * cl];
    #pragma unroll
    for (int cl = 0; cl < 2; ++cl) {
      ehv[cl] = eps_h[((size_t)t * 64 + B0 + bc) * 256 + U0 + v0 + 32 * cl];
      ecv[cl] = eps_c[((size_t)t * 64 + B0 + bc) * 256 + U0 + v0 + 32 * cl];
    }

    // ---- phase A: h(t-1) @ Whh (own 256 gate cols), weights in regs ----
    floatx4 acc0 = 0.f, acc1 = 0.f;
    #pragma unroll
    for (int kt = 0; kt < 8; ++kt) {
      bfx8 a = *(const bfx8*)&hA[(n * 256 + kt * 32 + quad * 8) ^ ((n & 7) << 3)];
      acc0 = __builtin_amdgcn_mfma_f32_16x16x32_bf16(a, BW[0][kt], acc0, 0, 0, 0);
      acc1 = __builtin_amdgcn_mfma_f32_16x16x32_bf16(a, BW[1][kt], acc1, 0, 0, 0);
    }
    #pragma unroll
    for (int r = 0; r < 4; ++r) {
      xg[quad * 4 + r][w * 32 + n]      = acc0[r];
      xg[quad * 4 + r][w * 32 + 16 + n] = acc1[r];
    }
    __syncthreads();

    // ---- activations + pre_c/pre_h (cell role); publish to group ----
    #pragma unroll
    for (int cl = 0; cl < 2; ++cl) {
      int v = v0 + 32 * cl, u = U0 + v;
      float gi = sigm(xg[bc][v]        + xw[0][cl]);
      float gf = sigm(xg[bc][64 + v]   + xw[1][cl]);
      float gg = tanhfast(xg[bc][128 + v] + xw[2][cl]);
      float go = sigm(xg[bc][192 + v]  + xw[3][cl]);
      float co = c_reg[cl];
      float pc = gf * co + gi * gg;
      float ph = go * tanhfast(co);  // OLD c
      preX[((size_t)(g * 2)     * 16 + bc) * 256 + u] = f2bf(ph);
      preX[((size_t)(g * 2 + 1) * 16 + bc) * 256 + u] = f2bf(pc);
    }
    gbar4(flags, g, bx, 2 * t + 1);

    // ---- gather full pre_h/pre_c into swizzled LDS ----
    #pragma unroll
    for (int j = 0; j < 2; ++j) {
      int f = (tid + 512 * j) * 8;               // short index in [0,8192)
      int buf = f >> 12, rem = f & 4095, b = rem >> 8, uu = rem & 255;
      bfx8 d = *(const bfx8*)(preX + (size_t)(g * 2 + buf) * 4096 + rem);
      *(bfx8*)&pA[buf][(b * 256 + uu) ^ ((b & 7) << 3)] = d;
    }
    __syncthreads();

    // ---- phase B: reparam (own 256 cols), weights in regs ----
    const short* Asrc = pA[(w < 4) ? 0 : 1];
    floatx4 racc0 = 0.f, racc1 = 0.f;
    #pragma unroll
    for (int kt = 0; kt < 8; ++kt) {
      bfx8 a = *(const bfx8*)&Asrc[(n * 256 + kt * 32 + quad * 8) ^ ((n & 7) << 3)];
      racc0 = __builtin_amdgcn_mfma_f32_16x16x32_bf16(a, BR[0][kt], racc0, 0, 0, 0);
      racc1 = __builtin_amdgcn_mfma_f32_16x16x32_bf16(a, BR[1][kt], racc1, 0, 0, 0);
    }
    {
      int cb = ((w < 4) ? 0 : 128) + (w & 3) * 32;  // mu_h|std_h|mu_c|std_c layout
      #pragma unroll
      for (int r = 0; r < 4; ++r) {
        xg[quad * 4 + r][cb + n]      = racc0[r];
        xg[quad * 4 + r][cb + 16 + n] = racc1[r];
      }
    }
    __syncthreads();

    // ---- sampling epilogue + outputs (cell role); publish h ----
    #pragma unroll
    for (int cl = 0; cl < 2; ++cl) {
      int v = v0 + 32 * cl, u = U0 + v;
      float mh = fminf(fmaxf(xg[bc][v], 1e-6f), 1e6f);
      float sh = fmaxf(softplusf(xg[bc][64 + v]), 1e-6f);
      float mc = fminf(fmaxf(xg[bc][128 + v], 1e-6f), 1e6f);
      float sc = fmaxf(softplusf(xg[bc][192 + v]), 1e-6f);
      float hn = mh + ehv[cl] * sh;
      float cn = mc + ecv[cl] * sc;
      c_reg[cl] = cn;
      htX[(size_t)g * 4096 + bc * 256 + u] = f2bf(hn);
      size_t o = ((size_t)(B0 + bc) * 512 + t) * 256 + u;
      ntst(hn, out + o);
      ntst(cn, out + OSTRIDE + o);
      ntst(mh, out + 2 * OSTRIDE + o);
      ntst(sh, out + 3 * OSTRIDE + o);
      ntst(mc, out + 4 * OSTRIDE + o);
      ntst(sc, out + 5 * OSTRIDE + o);
      if (t == 511) {
        ntst(hn, out + 6 * OSTRIDE + (size_t)(B0 + bc) * 256 + u);
        ntst(cn, out + 6 * OSTRIDE + 16384 + (size_t)(B0 + bc) * 256 + u);
      }
    }
    gbar4(flags, g, bx, 2 * t + 2);

    // ---- gather full h(t) into swizzled LDS for next phase A ----
    {
      int f = tid * 8;                           // short index in [0,4096)
      int b = f >> 8, uu = f & 255;
      *(bfx8*)&hA[(b * 256 + uu) ^ ((b & 7) << 3)] =
          *(const bfx8*)(htX + (size_t)g * 4096 + f);
    }
    __syncthreads();
  }
}

extern "C" void kernel_launch(void* const* d_in, const int* in_sizes, int n_in,
                              void* d_out, int out_size, void* d_ws, size_t ws_size,
                              hipStream_t stream) {
  (void)in_sizes; (void)n_in; (void)out_size;
  const float* x     = (const float*)d_in[0];
  const float* Wih   = (const float*)d_in[1];
  const float* Whh   = (const float*)d_in[2];
  const float* bias  = (const float*)d_in[3];
  const float* Hrep  = (const float*)d_in[4];
  const float* Crep  = (const float*)d_in[5];
  const float* eps_h = (const float*)d_in[6];
  const float* eps_c = (const float*)d_in[7];
  float* out = (float*)d_out;

  char* ws = (char*)d_ws;
  int*   flags = (int*)ws;                         // 1 KB (memset 4 KB)
  short* preX  = (short*)(ws + 4096);              // 64 KB: [4g][2][16][256] bf16
  short* htX   = (short*)(ws + 4096 + 65536);      // 32 KB: [4g][16][256] bf16
  const size_t packoff = 114688;                   // 112 KB
  short* WgP   = (short*)(ws + packoff);                             // 1 MB
  short* HrepP = (short*)(ws + packoff + (1 << 20));                 // 256 KB
  short* CrepP = (short*)(ws + packoff + (1 << 20) + (256 << 10));   // 256 KB
  const int packed = (ws_size >= packoff + (1 << 20) + (512 << 10)) ? 1 : 0;

  hipMemsetAsync(ws, 0, 4096, stream);  // reset barrier flags (capture-proven)
  if (packed)
    pack_kernel<<<dim3(3072), dim3(256), 0, stream>>>(Wih, Whh, Hrep, Crep,
                                                      WgP, HrepP, CrepP);
  xw_gemm_kernel<<<dim3(512, 4), dim3(256), 0, stream>>>(x, WgP, Wih, bias,
                                                         out, packed);
  recur_kernel<<<dim3(16), dim3(512), 0, stream>>>(
      WgP, HrepP, CrepP, Whh, Hrep, Crep, eps_h, eps_c, out,
      flags, preX, htX, packed);
}